// Round 1
// baseline (3415.184 us; speedup 1.0000x reference)
//
#include <hip/hip_runtime.h>

// SparseLinear: out[num_rows,128] = segment_sum(vals[i] * W[cols[i],:], rows[i]) + b
// Inputs (fp32/int32): vals[NNZ], rows[NNZ], cols[NNZ], W[8192,128], b[128], num_rows(scalar)
// Round 0: correctness baseline. init-with-bias + atomicAdd scatter.

#define UNITS 128

__global__ void init_bias_kernel(float* __restrict__ out,
                                 const float* __restrict__ b,
                                 int total4) {
    const float4* b4 = (const float4*)b;
    float4* out4 = (float4*)out;
    int stride = gridDim.x * blockDim.x;
    for (int j = blockIdx.x * blockDim.x + threadIdx.x; j < total4; j += stride) {
        out4[j] = b4[j & 31];   // UNITS/4 = 32 float4 per row
    }
}

__global__ void scatter_kernel(const float* __restrict__ vals,
                               const int* __restrict__ rows,
                               const int* __restrict__ cols,
                               const float* __restrict__ W,
                               float* __restrict__ out,
                               int nnz) {
    long long idx = (long long)blockIdx.x * blockDim.x + threadIdx.x;
    int i = (int)(idx >> 5);   // nonzero index (32 lanes per nnz)
    int c = (int)(idx & 31);   // float4 chunk within the 128-wide row
    if (i >= nnz) return;
    int row = rows[i];
    int col = cols[i];
    float v = vals[i];
    float4 w = ((const float4*)W)[col * 32 + c];   // coalesced 512B per nnz, L2-resident
    float* o = out + (size_t)row * UNITS + (c << 2);
    atomicAdd(o + 0, v * w.x);
    atomicAdd(o + 1, v * w.y);
    atomicAdd(o + 2, v * w.z);
    atomicAdd(o + 3, v * w.w);
}

extern "C" void kernel_launch(void* const* d_in, const int* in_sizes, int n_in,
                              void* d_out, int out_size, void* d_ws, size_t ws_size,
                              hipStream_t stream) {
    const float* vals = (const float*)d_in[0];
    const int*   rows = (const int*)d_in[1];
    const int*   cols = (const int*)d_in[2];
    const float* W    = (const float*)d_in[3];
    const float* b    = (const float*)d_in[4];
    float* out = (float*)d_out;

    int nnz = in_sizes[0];
    int total4 = out_size / 4;          // number of float4 elements in out

    // 1) out = broadcast(b)
    {
        int block = 256;
        int grid = 1024;                // grid-stride; 12.8M float4 / (1024*256) ~ 49 iters... bump it
        grid = (total4 + block - 1) / block;
        if (grid > 65535 * 8) grid = 65535 * 8;
        init_bias_kernel<<<grid, block, 0, stream>>>(out, b, total4);
    }

    // 2) scatter-add vals[i] * W[cols[i],:] into out[rows[i],:]
    {
        long long total_threads = (long long)nnz * 32;
        int block = 256;
        long long grid = (total_threads + block - 1) / block;
        scatter_kernel<<<(int)grid, block, 0, stream>>>(vals, rows, cols, W, out, nnz);
    }
}

// Round 2
// 481.129 us; speedup vs baseline: 7.0983x; 7.0983x over previous
//
#include <hip/hip_runtime.h>

// SparseLinear: out[NR,128] = segment_sum(vals[i] * W[cols[i],:], rows[i]) + b
// R1: counting-sort COO into row buckets (CSR), then one wave per row
// accumulates in registers -> single coalesced write. No fp32 atomics.

#define UNITS 128
#define SCAN_BLK 1024

// ---------- sort pipeline ----------

__global__ void hist_kernel(const int* __restrict__ rows, int* __restrict__ counts, int nnz) {
    int i = blockIdx.x * blockDim.x + threadIdx.x;
    if (i < nnz) atomicAdd(&counts[rows[i]], 1);
}

// per-chunk exclusive scan (chunk = 1024), chunk totals to bsums
__global__ void scan1_kernel(const int* __restrict__ counts, int* __restrict__ tmp,
                             int* __restrict__ bsums, int NR, int NS) {
    __shared__ int s[SCAN_BLK];
    int t = threadIdx.x;
    int i = blockIdx.x * SCAN_BLK + t;
    int x = (i < NR) ? counts[i] : 0;   // counts has NR entries; element NR is implicit 0
    s[t] = x;
    __syncthreads();
    for (int off = 1; off < SCAN_BLK; off <<= 1) {
        int v = (t >= off) ? s[t - off] : 0;
        __syncthreads();
        s[t] += v;
        __syncthreads();
    }
    if (i < NS) tmp[i] = s[t] - x;              // exclusive
    if (t == SCAN_BLK - 1) bsums[blockIdx.x] = s[SCAN_BLK - 1];
}

__global__ void scan2_kernel(int* __restrict__ bsums, int nb) {
    if (threadIdx.x == 0 && blockIdx.x == 0) {
        int run = 0;
        for (int i = 0; i < nb; ++i) { int c = bsums[i]; bsums[i] = run; run += c; }
    }
}

__global__ void scan3_kernel(const int* __restrict__ tmp, const int* __restrict__ bsums,
                             int* __restrict__ row_start, int* __restrict__ cursor,
                             int NR, int NS) {
    int i = blockIdx.x * blockDim.x + threadIdx.x;
    if (i < NS) {
        int v = tmp[i] + bsums[i >> 10];
        row_start[i] = v;
        if (i < NR) cursor[i] = v;
    }
}

__global__ void scatter_sort_kernel(const float* __restrict__ vals, const int* __restrict__ rows,
                                    const int* __restrict__ cols, int* __restrict__ cursor,
                                    float2* __restrict__ sorted, int nnz) {
    int i = blockIdx.x * blockDim.x + threadIdx.x;
    if (i < nnz) {
        int r = rows[i];
        int p = atomicAdd(&cursor[r], 1);
        sorted[p] = make_float2(vals[i], __int_as_float(cols[i]));
    }
}

// ---------- compute: one wave per row, float2 per lane ----------

__global__ void compute_kernel(const float2* __restrict__ sorted, const int* __restrict__ row_start,
                               const float* __restrict__ W, const float* __restrict__ b,
                               float* __restrict__ out, int NR) {
    int lane = threadIdx.x & 63;
    int wv = threadIdx.x >> 6;
    int row = blockIdx.x * 4 + wv;
    if (row >= NR) return;
    int start = row_start[row];
    int end = row_start[row + 1];
    const float2* W2 = (const float2*)W;
    float accx = 0.f, accy = 0.f;
    for (int j = start; j < end; ++j) {
        float2 p = sorted[j];                    // wave-uniform address -> broadcast
        int col = __float_as_int(p.y);
        float2 w = W2[col * 64 + lane];          // coalesced 512B/row-of-W per wave
        accx += p.x * w.x;
        accy += p.x * w.y;
    }
    float2 bb = ((const float2*)b)[lane];
    ((float2*)out)[(size_t)row * 64 + lane] = make_float2(accx + bb.x, accy + bb.y);
}

// ---------- fallback (R0 atomic path) if ws too small ----------

__global__ void init_bias_kernel(float* __restrict__ out, const float* __restrict__ b, int total4) {
    const float4* b4 = (const float4*)b;
    float4* out4 = (float4*)out;
    int stride = gridDim.x * blockDim.x;
    for (int j = blockIdx.x * blockDim.x + threadIdx.x; j < total4; j += stride)
        out4[j] = b4[j & 31];
}

__global__ void scatter_atomic_kernel(const float* __restrict__ vals, const int* __restrict__ rows,
                                      const int* __restrict__ cols, const float* __restrict__ W,
                                      float* __restrict__ out, int nnz) {
    long long idx = (long long)blockIdx.x * blockDim.x + threadIdx.x;
    int i = (int)(idx >> 5);
    int c = (int)(idx & 31);
    if (i >= nnz) return;
    int row = rows[i], col = cols[i];
    float v = vals[i];
    float4 w = ((const float4*)W)[col * 32 + c];
    float* o = out + (size_t)row * UNITS + (c << 2);
    atomicAdd(o + 0, v * w.x);
    atomicAdd(o + 1, v * w.y);
    atomicAdd(o + 2, v * w.z);
    atomicAdd(o + 3, v * w.w);
}

extern "C" void kernel_launch(void* const* d_in, const int* in_sizes, int n_in,
                              void* d_out, int out_size, void* d_ws, size_t ws_size,
                              hipStream_t stream) {
    const float* vals = (const float*)d_in[0];
    const int*   rows = (const int*)d_in[1];
    const int*   cols = (const int*)d_in[2];
    const float* W    = (const float*)d_in[3];
    const float* b    = (const float*)d_in[4];
    float* out = (float*)d_out;

    const int nnz = in_sizes[0];
    const int NR  = out_size / UNITS;       // num_rows (scalar input is device-side; derive from out)
    const int NS  = NR + 1;
    const int NB  = (NS + SCAN_BLK - 1) / SCAN_BLK;

    // workspace layout (256B aligned)
    auto align = [](size_t x) { return (x + 255) & ~(size_t)255; };
    size_t off_counts   = 0;
    size_t off_tmp      = align(off_counts + (size_t)NR * 4);
    size_t off_bsums    = align(off_tmp    + (size_t)NS * 4);
    size_t off_rowstart = align(off_bsums  + (size_t)NB * 4);
    size_t off_cursor   = align(off_rowstart + (size_t)NS * 4);
    size_t off_sorted   = align(off_cursor + (size_t)NR * 4);
    size_t needed       = off_sorted + (size_t)nnz * 8;

    if (ws_size < needed) {
        // fallback: R0 atomic path
        int total4 = out_size / 4;
        int block = 256;
        int grid = (total4 + block - 1) / block;
        init_bias_kernel<<<grid, block, 0, stream>>>(out, b, total4);
        long long total_threads = (long long)nnz * 32;
        long long g2 = (total_threads + block - 1) / block;
        scatter_atomic_kernel<<<(int)g2, block, 0, stream>>>(vals, rows, cols, W, out, nnz);
        return;
    }

    char* ws = (char*)d_ws;
    int*    counts    = (int*)(ws + off_counts);
    int*    tmp       = (int*)(ws + off_tmp);
    int*    bsums     = (int*)(ws + off_bsums);
    int*    row_start = (int*)(ws + off_rowstart);
    int*    cursor    = (int*)(ws + off_cursor);
    float2* sorted    = (float2*)(ws + off_sorted);

    hipMemsetAsync(counts, 0, (size_t)NR * 4, stream);

    {   // histogram
        int block = 256, grid = (nnz + block - 1) / block;
        hist_kernel<<<grid, block, 0, stream>>>(rows, counts, nnz);
    }
    {   // exclusive scan of counts -> row_start (and cursor copy)
        scan1_kernel<<<NB, SCAN_BLK, 0, stream>>>(counts, tmp, bsums, NR, NS);
        scan2_kernel<<<1, 64, 0, stream>>>(bsums, NB);
        int block = 256, grid = (NS + block - 1) / block;
        scan3_kernel<<<grid, block, 0, stream>>>(tmp, bsums, row_start, cursor, NR, NS);
    }
    {   // bucket-scatter (val,col) pairs by row
        int block = 256, grid = (nnz + block - 1) / block;
        scatter_sort_kernel<<<grid, block, 0, stream>>>(vals, rows, cols, cursor, sorted, nnz);
    }
    {   // per-row register accumulation + bias + single write
        int rows_per_block = 4;  // 256 threads = 4 waves
        int grid = (NR + rows_per_block - 1) / rows_per_block;
        compute_kernel<<<grid, 256, 0, stream>>>(sorted, row_start, W, b, out, NR);
    }
}

// Round 3
// 402.842 us; speedup vs baseline: 8.4777x; 1.1943x over previous
//
#include <hip/hip_runtime.h>

// SparseLinear: out[NR,128] = segment_sum(vals[i] * W[cols[i],:], rows[i]) + b
// R2: compute kernel v2 — coalesced bucket load + readlane broadcast + 4-wide
// independent W gathers (ILP). Sort pipeline unchanged from R1.

#define UNITS 128
#define SCAN_BLK 1024

// ---------- sort pipeline ----------

__global__ void hist_kernel(const int* __restrict__ rows, int* __restrict__ counts, int nnz) {
    int i = blockIdx.x * blockDim.x + threadIdx.x;
    if (i < nnz) atomicAdd(&counts[rows[i]], 1);
}

__global__ void scan1_kernel(const int* __restrict__ counts, int* __restrict__ tmp,
                             int* __restrict__ bsums, int NR, int NS) {
    __shared__ int s[SCAN_BLK];
    int t = threadIdx.x;
    int i = blockIdx.x * SCAN_BLK + t;
    int x = (i < NR) ? counts[i] : 0;
    s[t] = x;
    __syncthreads();
    for (int off = 1; off < SCAN_BLK; off <<= 1) {
        int v = (t >= off) ? s[t - off] : 0;
        __syncthreads();
        s[t] += v;
        __syncthreads();
    }
    if (i < NS) tmp[i] = s[t] - x;
    if (t == SCAN_BLK - 1) bsums[blockIdx.x] = s[SCAN_BLK - 1];
}

__global__ void scan2_kernel(int* __restrict__ bsums, int nb) {
    if (threadIdx.x == 0 && blockIdx.x == 0) {
        int run = 0;
        for (int i = 0; i < nb; ++i) { int c = bsums[i]; bsums[i] = run; run += c; }
    }
}

__global__ void scan3_kernel(const int* __restrict__ tmp, const int* __restrict__ bsums,
                             int* __restrict__ row_start, int* __restrict__ cursor,
                             int NR, int NS) {
    int i = blockIdx.x * blockDim.x + threadIdx.x;
    if (i < NS) {
        int v = tmp[i] + bsums[i >> 10];
        row_start[i] = v;
        if (i < NR) cursor[i] = v;
    }
}

__global__ void scatter_sort_kernel(const float* __restrict__ vals, const int* __restrict__ rows,
                                    const int* __restrict__ cols, int* __restrict__ cursor,
                                    float2* __restrict__ sorted, int nnz) {
    int i = blockIdx.x * blockDim.x + threadIdx.x;
    if (i < nnz) {
        int r = rows[i];
        int p = atomicAdd(&cursor[r], 1);
        sorted[p] = make_float2(vals[i], __int_as_float(cols[i]));
    }
}

// ---------- compute v2: wave/row, coalesced pair load + readlane broadcast ----------

__global__ void compute_kernel(const float2* __restrict__ sorted, const int* __restrict__ row_start,
                               const float* __restrict__ W, const float* __restrict__ b,
                               float* __restrict__ out, int NR) {
    int lane = threadIdx.x & 63;
    int wv = threadIdx.x >> 6;
    int row = blockIdx.x * 4 + wv;
    if (row >= NR) return;
    int start = row_start[row];
    int end   = row_start[row + 1];
    const float2* W2 = (const float2*)W;
    float accx0 = 0.f, accy0 = 0.f, accx1 = 0.f, accy1 = 0.f;

    for (int base = start; base < end; base += 64) {
        int m = end - base;
        if (m > 64) m = 64;
        float2 p = make_float2(0.f, __int_as_float(0));
        if (lane < m) p = sorted[base + lane];          // one coalesced load per chunk
        int vi = __float_as_int(p.x);
        int ci = __float_as_int(p.y);
        int rounds = (m + 3) & ~3;                       // pad with zero pairs (v=0,col=0)
        for (int j = 0; j < rounds; j += 4) {
            float v0 = __int_as_float(__builtin_amdgcn_readlane(vi, j));
            int   c0 = __builtin_amdgcn_readlane(ci, j);
            float v1 = __int_as_float(__builtin_amdgcn_readlane(vi, j + 1));
            int   c1 = __builtin_amdgcn_readlane(ci, j + 1);
            float v2 = __int_as_float(__builtin_amdgcn_readlane(vi, j + 2));
            int   c2 = __builtin_amdgcn_readlane(ci, j + 2);
            float v3 = __int_as_float(__builtin_amdgcn_readlane(vi, j + 3));
            int   c3 = __builtin_amdgcn_readlane(ci, j + 3);
            float2 w0 = W2[c0 * 64 + lane];              // 4 independent L2 gathers in flight
            float2 w1 = W2[c1 * 64 + lane];
            float2 w2 = W2[c2 * 64 + lane];
            float2 w3 = W2[c3 * 64 + lane];
            accx0 += v0 * w0.x; accy0 += v0 * w0.y;
            accx1 += v1 * w1.x; accy1 += v1 * w1.y;
            accx0 += v2 * w2.x; accy0 += v2 * w2.y;
            accx1 += v3 * w3.x; accy1 += v3 * w3.y;
        }
    }
    float2 bb = ((const float2*)b)[lane];
    ((float2*)out)[(size_t)row * 64 + lane] =
        make_float2(accx0 + accx1 + bb.x, accy0 + accy1 + bb.y);
}

// ---------- fallback (atomic path) if ws too small ----------

__global__ void init_bias_kernel(float* __restrict__ out, const float* __restrict__ b, int total4) {
    const float4* b4 = (const float4*)b;
    float4* out4 = (float4*)out;
    int stride = gridDim.x * blockDim.x;
    for (int j = blockIdx.x * blockDim.x + threadIdx.x; j < total4; j += stride)
        out4[j] = b4[j & 31];
}

__global__ void scatter_atomic_kernel(const float* __restrict__ vals, const int* __restrict__ rows,
                                      const int* __restrict__ cols, const float* __restrict__ W,
                                      float* __restrict__ out, int nnz) {
    long long idx = (long long)blockIdx.x * blockDim.x + threadIdx.x;
    int i = (int)(idx >> 5);
    int c = (int)(idx & 31);
    if (i >= nnz) return;
    int row = rows[i], col = cols[i];
    float v = vals[i];
    float4 w = ((const float4*)W)[col * 32 + c];
    float* o = out + (size_t)row * UNITS + (c << 2);
    atomicAdd(o + 0, v * w.x);
    atomicAdd(o + 1, v * w.y);
    atomicAdd(o + 2, v * w.z);
    atomicAdd(o + 3, v * w.w);
}

extern "C" void kernel_launch(void* const* d_in, const int* in_sizes, int n_in,
                              void* d_out, int out_size, void* d_ws, size_t ws_size,
                              hipStream_t stream) {
    const float* vals = (const float*)d_in[0];
    const int*   rows = (const int*)d_in[1];
    const int*   cols = (const int*)d_in[2];
    const float* W    = (const float*)d_in[3];
    const float* b    = (const float*)d_in[4];
    float* out = (float*)d_out;

    const int nnz = in_sizes[0];
    const int NR  = out_size / UNITS;
    const int NS  = NR + 1;
    const int NB  = (NS + SCAN_BLK - 1) / SCAN_BLK;

    auto align = [](size_t x) { return (x + 255) & ~(size_t)255; };
    size_t off_counts   = 0;
    size_t off_tmp      = align(off_counts + (size_t)NR * 4);
    size_t off_bsums    = align(off_tmp    + (size_t)NS * 4);
    size_t off_rowstart = align(off_bsums  + (size_t)NB * 4);
    size_t off_cursor   = align(off_rowstart + (size_t)NS * 4);
    size_t off_sorted   = align(off_cursor + (size_t)NR * 4);
    size_t needed       = off_sorted + (size_t)nnz * 8;

    if (ws_size < needed) {
        int total4 = out_size / 4;
        int block = 256;
        int grid = (total4 + block - 1) / block;
        init_bias_kernel<<<grid, block, 0, stream>>>(out, b, total4);
        long long total_threads = (long long)nnz * 32;
        long long g2 = (total_threads + block - 1) / block;
        scatter_atomic_kernel<<<(int)g2, block, 0, stream>>>(vals, rows, cols, W, out, nnz);
        return;
    }

    char* ws = (char*)d_ws;
    int*    counts    = (int*)(ws + off_counts);
    int*    tmp       = (int*)(ws + off_tmp);
    int*    bsums     = (int*)(ws + off_bsums);
    int*    row_start = (int*)(ws + off_rowstart);
    int*    cursor    = (int*)(ws + off_cursor);
    float2* sorted    = (float2*)(ws + off_sorted);

    hipMemsetAsync(counts, 0, (size_t)NR * 4, stream);

    {
        int block = 256, grid = (nnz + block - 1) / block;
        hist_kernel<<<grid, block, 0, stream>>>(rows, counts, nnz);
    }
    {
        scan1_kernel<<<NB, SCAN_BLK, 0, stream>>>(counts, tmp, bsums, NR, NS);
        scan2_kernel<<<1, 64, 0, stream>>>(bsums, NB);
        int block = 256, grid = (NS + block - 1) / block;
        scan3_kernel<<<grid, block, 0, stream>>>(tmp, bsums, row_start, cursor, NR, NS);
    }
    {
        int block = 256, grid = (nnz + block - 1) / block;
        scatter_sort_kernel<<<grid, block, 0, stream>>>(vals, rows, cols, cursor, sorted, nnz);
    }
    {
        int rows_per_block = 4;
        int grid = (NR + rows_per_block - 1) / rows_per_block;
        compute_kernel<<<grid, 256, 0, stream>>>(sorted, row_start, W, b, out, NR);
    }
}

// Round 4
// 291.148 us; speedup vs baseline: 11.7300x; 1.3836x over previous
//
#include <hip/hip_runtime.h>

// SparseLinear: out[NR,128] = segment_sum(vals[i] * W[cols[i],:], rows[i]) + b
// R3: hierarchical sort for coalesced writes.
//   partition_kernel: LDS-staged partition by row>>8 (grouped, mostly-coalesced writes)
//   fine_sort_kernel: per-coarse-bucket exact row sort via LDS, coalesced in/out
//   compute_kernel:   unchanged from R2 (wave/row, readlane broadcast, 4-wide ILP)

#define UNITS 128
#define SCAN_BLK 1024
#define CH 4096          // partition chunk per block
#define NBC_SLOTS 512    // padded coarse-bucket count (actual ~391)
#define FCAP 6912        // fine-sort LDS capacity (entries); mean bucket = 5120, sigma ~72

// ---------- histogram + scan (row_start) ----------

__global__ void hist_kernel(const int* __restrict__ rows, int* __restrict__ counts, int nnz) {
    int i = blockIdx.x * blockDim.x + threadIdx.x;
    if (i < nnz) atomicAdd(&counts[rows[i]], 1);
}

__global__ void scan1_kernel(const int* __restrict__ counts, int* __restrict__ tmp,
                             int* __restrict__ bsums, int NR, int NS) {
    __shared__ int s[SCAN_BLK];
    int t = threadIdx.x;
    int i = blockIdx.x * SCAN_BLK + t;
    int x = (i < NR) ? counts[i] : 0;
    s[t] = x;
    __syncthreads();
    for (int off = 1; off < SCAN_BLK; off <<= 1) {
        int v = (t >= off) ? s[t - off] : 0;
        __syncthreads();
        s[t] += v;
        __syncthreads();
    }
    if (i < NS) tmp[i] = s[t] - x;
    if (t == SCAN_BLK - 1) bsums[blockIdx.x] = s[SCAN_BLK - 1];
}

__global__ void scan2_kernel(int* __restrict__ bsums, int nb) {
    if (threadIdx.x == 0 && blockIdx.x == 0) {
        int run = 0;
        for (int i = 0; i < nb; ++i) { int c = bsums[i]; bsums[i] = run; run += c; }
    }
}

__global__ void scan3_kernel(const int* __restrict__ tmp, const int* __restrict__ bsums,
                             int* __restrict__ row_start, int* __restrict__ cursor,
                             int* __restrict__ ccur, int NR, int NS, int nbc) {
    int i = blockIdx.x * blockDim.x + threadIdx.x;
    if (i < NS) {
        int v = tmp[i] + bsums[i >> 10];
        row_start[i] = v;
        if (i < NR) cursor[i] = v;
    }
    if (i < nbc) {
        // coarse bucket b covers rows [b<<8, (b+1)<<8); its range starts at row_start[b<<8]
        ccur[i] = tmp[i << 8] + bsums[(i << 8) >> 10];
    }
}

// ---------- phase A: LDS-staged partition by row>>8 ----------

__global__ __launch_bounds__(256) void partition_kernel(
        const float* __restrict__ vals, const int* __restrict__ rows,
        const int* __restrict__ cols, int* __restrict__ ccur,
        float2* __restrict__ sortedA, int nnz, int nbc) {
    __shared__ float2 staged[CH];              // 32 KB: (val, packed(col|rowlo<<13))
    __shared__ unsigned short bktid[CH];       //  8 KB
    __shared__ unsigned short invs[CH];        //  8 KB
    __shared__ int hist[NBC_SLOTS];            //  2 KB (also reused as rank cursor)
    __shared__ int pref[NBC_SLOTS];            //  2 KB
    __shared__ int gdelta[NBC_SLOTS];          //  2 KB

    const int t = threadIdx.x;                 // 256 threads
    const int chunk0 = blockIdx.x * CH;
    int n = nnz - chunk0;
    if (n > CH) n = CH;

    hist[t] = 0; hist[t + 256] = 0;
    __syncthreads();

    // round A: load + stage + LDS histogram
    for (int r = t; r < n; r += 256) {
        int i = chunk0 + r;
        int row = rows[i];
        int col = cols[i];
        float v = vals[i];
        int b = row >> 8;
        staged[r] = make_float2(v, __int_as_float(col | ((row & 255) << 13)));
        bktid[r] = (unsigned short)b;
        atomicAdd(&hist[b], 1);
    }
    __syncthreads();

    // inclusive block scan of hist over 512 slots (2 per thread)
    const int b0 = t, b1 = t + 256;
    pref[b0] = hist[b0]; pref[b1] = hist[b1];
    __syncthreads();
    for (int off = 1; off < NBC_SLOTS; off <<= 1) {
        int a0 = (b0 >= off) ? pref[b0 - off] : 0;
        int a1 = (b1 >= off) ? pref[b1 - off] : 0;
        __syncthreads();
        pref[b0] += a0; pref[b1] += a1;
        __syncthreads();
    }

    // reserve global ranges, compute write deltas, reset cursors to local excl prefix
    int c0 = hist[b0], c1 = hist[b1];
    int ex0 = pref[b0] - c0, ex1 = pref[b1] - c1;
    if (b0 < nbc) {
        int g = (c0 > 0) ? atomicAdd(&ccur[b0], c0) : 0;
        gdelta[b0] = g - ex0;
    }
    if (b1 < nbc) {
        int g = (c1 > 0) ? atomicAdd(&ccur[b1], c1) : 0;
        gdelta[b1] = g - ex1;
    }
    __syncthreads();
    hist[b0] = ex0; hist[b1] = ex1;
    __syncthreads();

    // round B1: local ranks -> inverse permutation
    for (int r = t; r < n; r += 256) {
        int pos = atomicAdd(&hist[bktid[r]], 1);
        invs[pos] = (unsigned short)r;
    }
    __syncthreads();

    // round B2: emit in bucket-grouped order (runs of consecutive dests)
    for (int s = t; s < n; s += 256) {
        int i = invs[s];
        float2 e = staged[i];
        int b = bktid[i];
        sortedA[gdelta[b] + s] = e;
    }
}

// ---------- phase B: exact row sort within each coarse bucket ----------

__global__ __launch_bounds__(256) void fine_sort_kernel(
        const float2* __restrict__ A, float2* __restrict__ B,
        const int* __restrict__ row_start, int NR) {
    __shared__ float2 st[FCAP];     // 54 KB
    __shared__ int cur[256];
    int bb = blockIdx.x;
    int r0 = bb << 8;
    int nr = NR - r0; if (nr > 256) nr = 256;
    int gstart = row_start[r0];
    int gend = row_start[r0 + nr];
    int cnt = gend - gstart;
    int t = threadIdx.x;
    for (int r = t; r < nr; r += 256) cur[r] = row_start[r0 + r] - gstart;
    __syncthreads();
    if (cnt <= FCAP) {
        for (int k = t; k < cnt; k += 256) {
            float2 e = A[gstart + k];                  // coalesced read
            int packed = __float_as_int(e.y);
            int pos = atomicAdd(&cur[(packed >> 13) & 255], 1);
            st[pos] = make_float2(e.x, __int_as_float(packed & 8191));  // LDS scatter
        }
        __syncthreads();
        for (int k = t; k < cnt; k += 256)
            B[gstart + k] = st[k];                     // coalesced write
    } else {
        // overflow (practically impossible): direct scatter, dual-buffer-safe
        for (int k = t; k < cnt; k += 256) {
            float2 e = A[gstart + k];
            int packed = __float_as_int(e.y);
            int pos = atomicAdd(&cur[(packed >> 13) & 255], 1);
            B[gstart + pos] = make_float2(e.x, __int_as_float(packed & 8191));
        }
    }
}

// ---------- legacy scatter (fallback tier 2) ----------

__global__ void scatter_sort_kernel(const float* __restrict__ vals, const int* __restrict__ rows,
                                    const int* __restrict__ cols, int* __restrict__ cursor,
                                    float2* __restrict__ sorted, int nnz) {
    int i = blockIdx.x * blockDim.x + threadIdx.x;
    if (i < nnz) {
        int r = rows[i];
        int p = atomicAdd(&cursor[r], 1);
        sorted[p] = make_float2(vals[i], __int_as_float(cols[i]));
    }
}

// ---------- compute: wave/row, coalesced pair load + readlane broadcast ----------

__global__ void compute_kernel(const float2* __restrict__ sorted, const int* __restrict__ row_start,
                               const float* __restrict__ W, const float* __restrict__ b,
                               float* __restrict__ out, int NR) {
    int lane = threadIdx.x & 63;
    int wv = threadIdx.x >> 6;
    int row = blockIdx.x * 4 + wv;
    if (row >= NR) return;
    int start = row_start[row];
    int end   = row_start[row + 1];
    const float2* W2 = (const float2*)W;
    float accx0 = 0.f, accy0 = 0.f, accx1 = 0.f, accy1 = 0.f;

    for (int base = start; base < end; base += 64) {
        int m = end - base;
        if (m > 64) m = 64;
        float2 p = make_float2(0.f, __int_as_float(0));
        if (lane < m) p = sorted[base + lane];
        int vi = __float_as_int(p.x);
        int ci = __float_as_int(p.y);
        int rounds = (m + 3) & ~3;
        for (int j = 0; j < rounds; j += 4) {
            float v0 = __int_as_float(__builtin_amdgcn_readlane(vi, j));
            int   c0 = __builtin_amdgcn_readlane(ci, j);
            float v1 = __int_as_float(__builtin_amdgcn_readlane(vi, j + 1));
            int   c1 = __builtin_amdgcn_readlane(ci, j + 1);
            float v2 = __int_as_float(__builtin_amdgcn_readlane(vi, j + 2));
            int   c2 = __builtin_amdgcn_readlane(ci, j + 2);
            float v3 = __int_as_float(__builtin_amdgcn_readlane(vi, j + 3));
            int   c3 = __builtin_amdgcn_readlane(ci, j + 3);
            float2 w0 = W2[c0 * 64 + lane];
            float2 w1 = W2[c1 * 64 + lane];
            float2 w2 = W2[c2 * 64 + lane];
            float2 w3 = W2[c3 * 64 + lane];
            accx0 += v0 * w0.x; accy0 += v0 * w0.y;
            accx1 += v1 * w1.x; accy1 += v1 * w1.y;
            accx0 += v2 * w2.x; accy0 += v2 * w2.y;
            accx1 += v3 * w3.x; accy1 += v3 * w3.y;
        }
    }
    float2 bb = ((const float2*)b)[lane];
    ((float2*)out)[(size_t)row * 64 + lane] =
        make_float2(accx0 + accx1 + bb.x, accy0 + accy1 + bb.y);
}

// ---------- fallback tier 3 (atomic path) ----------

__global__ void init_bias_kernel(float* __restrict__ out, const float* __restrict__ b, int total4) {
    const float4* b4 = (const float4*)b;
    float4* out4 = (float4*)out;
    int stride = gridDim.x * blockDim.x;
    for (int j = blockIdx.x * blockDim.x + threadIdx.x; j < total4; j += stride)
        out4[j] = b4[j & 31];
}

__global__ void scatter_atomic_kernel(const float* __restrict__ vals, const int* __restrict__ rows,
                                      const int* __restrict__ cols, const float* __restrict__ W,
                                      float* __restrict__ out, int nnz) {
    long long idx = (long long)blockIdx.x * blockDim.x + threadIdx.x;
    int i = (int)(idx >> 5);
    int c = (int)(idx & 31);
    if (i >= nnz) return;
    int row = rows[i], col = cols[i];
    float v = vals[i];
    float4 w = ((const float4*)W)[col * 32 + c];
    float* o = out + (size_t)row * UNITS + (c << 2);
    atomicAdd(o + 0, v * w.x);
    atomicAdd(o + 1, v * w.y);
    atomicAdd(o + 2, v * w.z);
    atomicAdd(o + 3, v * w.w);
}

extern "C" void kernel_launch(void* const* d_in, const int* in_sizes, int n_in,
                              void* d_out, int out_size, void* d_ws, size_t ws_size,
                              hipStream_t stream) {
    const float* vals = (const float*)d_in[0];
    const int*   rows = (const int*)d_in[1];
    const int*   cols = (const int*)d_in[2];
    const float* W    = (const float*)d_in[3];
    const float* b    = (const float*)d_in[4];
    float* out = (float*)d_out;

    const int nnz = in_sizes[0];
    const int NR  = out_size / UNITS;
    const int NS  = NR + 1;
    const int NB  = (NS + SCAN_BLK - 1) / SCAN_BLK;
    const int nbc = (NR + 255) >> 8;

    auto align = [](size_t x) { return (x + 255) & ~(size_t)255; };
    size_t off_counts   = 0;
    size_t off_tmp      = align(off_counts + (size_t)NR * 4);
    size_t off_bsums    = align(off_tmp    + (size_t)NS * 4);
    size_t off_rowstart = align(off_bsums  + (size_t)NB * 4);
    size_t off_cursor   = align(off_rowstart + (size_t)NS * 4);
    size_t off_ccur     = align(off_cursor + (size_t)NR * 4);
    size_t off_sortedA  = align(off_ccur   + (size_t)nbc * 4);
    size_t off_sortedB  = align(off_sortedA + (size_t)nnz * 8);
    size_t needed_full  = off_sortedB + (size_t)nnz * 8;   // ~34 MB
    size_t needed_r2    = off_sortedA + (size_t)nnz * 8;   // ~18 MB (tier-2)

    if (ws_size < needed_r2) {
        // tier 3: atomic path
        int total4 = out_size / 4;
        int block = 256;
        int grid = (total4 + block - 1) / block;
        init_bias_kernel<<<grid, block, 0, stream>>>(out, b, total4);
        long long total_threads = (long long)nnz * 32;
        long long g2 = (total_threads + block - 1) / block;
        scatter_atomic_kernel<<<(int)g2, block, 0, stream>>>(vals, rows, cols, W, out, nnz);
        return;
    }

    char* ws = (char*)d_ws;
    int*    counts    = (int*)(ws + off_counts);
    int*    tmp       = (int*)(ws + off_tmp);
    int*    bsums     = (int*)(ws + off_bsums);
    int*    row_start = (int*)(ws + off_rowstart);
    int*    cursor    = (int*)(ws + off_cursor);
    int*    ccur      = (int*)(ws + off_ccur);
    float2* sortedA   = (float2*)(ws + off_sortedA);

    hipMemsetAsync(counts, 0, (size_t)NR * 4, stream);

    {   // per-row histogram
        int block = 256, grid = (nnz + block - 1) / block;
        hist_kernel<<<grid, block, 0, stream>>>(rows, counts, nnz);
    }
    {   // exclusive scan -> row_start, per-row cursor (tier-2), coarse cursors
        scan1_kernel<<<NB, SCAN_BLK, 0, stream>>>(counts, tmp, bsums, NR, NS);
        scan2_kernel<<<1, 64, 0, stream>>>(bsums, NB);
        int block = 256, grid = (NS + block - 1) / block;
        scan3_kernel<<<grid, block, 0, stream>>>(tmp, bsums, row_start, cursor, ccur, NR, NS, nbc);
    }

    if (ws_size >= needed_full) {
        float2* sortedB = (float2*)(ws + off_sortedB);
        {   // phase A: coarse partition (coalesced grouped writes)
            int grid = (nnz + CH - 1) / CH;
            partition_kernel<<<grid, 256, 0, stream>>>(vals, rows, cols, ccur, sortedA, nnz, nbc);
        }
        {   // phase B: exact row order within buckets
            fine_sort_kernel<<<nbc, 256, 0, stream>>>(sortedA, sortedB, row_start, NR);
        }
        {   // compute
            int grid = (NR + 3) / 4;
            compute_kernel<<<grid, 256, 0, stream>>>(sortedB, row_start, W, b, out, NR);
        }
    } else {
        // tier 2: R2 pipeline (direct global scatter sort)
        {
            int block = 256, grid = (nnz + block - 1) / block;
            scatter_sort_kernel<<<grid, block, 0, stream>>>(vals, rows, cols, cursor, sortedA, nnz);
        }
        {
            int grid = (NR + 3) / 4;
            compute_kernel<<<grid, 256, 0, stream>>>(sortedA, row_start, W, b, out, NR);
        }
    }
}

// Round 5
// 215.678 us; speedup vs baseline: 15.8346x; 1.3499x over previous
//
#include <hip/hip_runtime.h>

// SparseLinear: out[NR,128] = segment_sum(vals[i] * W[cols[i],:], rows[i]) + b
// R4: kill the per-row global histogram.
//   coarse_hist (LDS-privatized, 391 coarse counters) -> coarse_scan (1 block)
//   partition_kernel: LDS-staged partition by row>>8 (unchanged from R3)
//   fine_sort_kernel v2: per-bucket exact row sort + derives row_start in-block
//   compute_kernel: unchanged (wave/row, readlane broadcast, 4-wide ILP)

#define UNITS 128
#define SCAN_BLK 1024
#define CH 4096          // partition chunk per block
#define NBC_SLOTS 512    // padded coarse-bucket count (actual ~391)
#define FCAP 6912        // fine-sort LDS capacity; mean bucket 5120, sigma ~72

// ---------- fast path: coarse histogram + scan ----------

__global__ __launch_bounds__(256) void coarse_hist_kernel(
        const int* __restrict__ rows, int* __restrict__ ccount, int nnz, int nbc) {
    __shared__ int h[NBC_SLOTS];
    int t = threadIdx.x;
    h[t] = 0; h[t + 256] = 0;
    __syncthreads();
    int stride = gridDim.x * blockDim.x;
    for (int i = blockIdx.x * blockDim.x + t; i < nnz; i += stride)
        atomicAdd(&h[rows[i] >> 8], 1);
    __syncthreads();
    int c0 = h[t], c1 = h[t + 256];
    if (c0 && t < nbc) atomicAdd(&ccount[t], c0);
    if (c1 && t + 256 < nbc) atomicAdd(&ccount[t + 256], c1);
}

__global__ void coarse_scan_kernel(const int* __restrict__ ccount, int* __restrict__ cstart,
                                   int* __restrict__ ccur, int nbc) {
    __shared__ int s[NBC_SLOTS];
    int t = threadIdx.x;            // 512 threads
    int x = (t < nbc) ? ccount[t] : 0;
    s[t] = x;
    __syncthreads();
    for (int off = 1; off < NBC_SLOTS; off <<= 1) {
        int v = (t >= off) ? s[t - off] : 0;
        __syncthreads();
        s[t] += v;
        __syncthreads();
    }
    int excl = s[t] - x;
    if (t <= nbc) cstart[t] = excl;          // cstart[nbc] = total nnz
    if (t < nbc) ccur[t] = excl;
}

// ---------- phase A: LDS-staged partition by row>>8 ----------

__global__ __launch_bounds__(256) void partition_kernel(
        const float* __restrict__ vals, const int* __restrict__ rows,
        const int* __restrict__ cols, int* __restrict__ ccur,
        float2* __restrict__ sortedA, int nnz, int nbc) {
    __shared__ float2 staged[CH];              // 32 KB: (val, packed(col|rowlo<<13))
    __shared__ unsigned short bktid[CH];       //  8 KB
    __shared__ unsigned short invs[CH];        //  8 KB
    __shared__ int hist[NBC_SLOTS];            //  2 KB (reused as rank cursor)
    __shared__ int pref[NBC_SLOTS];            //  2 KB
    __shared__ int gdelta[NBC_SLOTS];          //  2 KB

    const int t = threadIdx.x;                 // 256 threads
    const int chunk0 = blockIdx.x * CH;
    int n = nnz - chunk0;
    if (n > CH) n = CH;

    hist[t] = 0; hist[t + 256] = 0;
    __syncthreads();

    for (int r = t; r < n; r += 256) {
        int i = chunk0 + r;
        int row = rows[i];
        int col = cols[i];
        float v = vals[i];
        int b = row >> 8;
        staged[r] = make_float2(v, __int_as_float(col | ((row & 255) << 13)));
        bktid[r] = (unsigned short)b;
        atomicAdd(&hist[b], 1);
    }
    __syncthreads();

    const int b0 = t, b1 = t + 256;
    pref[b0] = hist[b0]; pref[b1] = hist[b1];
    __syncthreads();
    for (int off = 1; off < NBC_SLOTS; off <<= 1) {
        int a0 = (b0 >= off) ? pref[b0 - off] : 0;
        int a1 = (b1 >= off) ? pref[b1 - off] : 0;
        __syncthreads();
        pref[b0] += a0; pref[b1] += a1;
        __syncthreads();
    }

    int c0 = hist[b0], c1 = hist[b1];
    int ex0 = pref[b0] - c0, ex1 = pref[b1] - c1;
    if (b0 < nbc) {
        int g = (c0 > 0) ? atomicAdd(&ccur[b0], c0) : 0;
        gdelta[b0] = g - ex0;
    }
    if (b1 < nbc) {
        int g = (c1 > 0) ? atomicAdd(&ccur[b1], c1) : 0;
        gdelta[b1] = g - ex1;
    }
    __syncthreads();
    hist[b0] = ex0; hist[b1] = ex1;
    __syncthreads();

    for (int r = t; r < n; r += 256) {
        int pos = atomicAdd(&hist[bktid[r]], 1);
        invs[pos] = (unsigned short)r;
    }
    __syncthreads();

    for (int s = t; s < n; s += 256) {
        int i = invs[s];
        float2 e = staged[i];
        int b = bktid[i];
        sortedA[gdelta[b] + s] = e;
    }
}

// ---------- phase B: exact row sort within bucket + derive row_start ----------

__global__ __launch_bounds__(256) void fine_sort_kernel(
        const float2* __restrict__ A, float2* __restrict__ B,
        const int* __restrict__ cstart, int* __restrict__ row_start,
        int NR, int nnz, int nbc) {
    __shared__ float2 st[FCAP];     // 54 KB
    __shared__ int cnt_s[256];
    __shared__ int pref_s[256];
    int bb = blockIdx.x;
    int r0 = bb << 8;
    int nr = NR - r0; if (nr > 256) nr = 256;
    int gstart = cstart[bb];
    int gend   = cstart[bb + 1];
    int cnt = gend - gstart;
    int t = threadIdx.x;
    cnt_s[t] = 0;
    __syncthreads();

    // pass 1: histogram row-lows (read only the packed int, coalesced-ish)
    const int* Ai = (const int*)A;
    for (int k = t; k < cnt; k += 256) {
        int packed = Ai[2 * (gstart + k) + 1];
        atomicAdd(&cnt_s[(packed >> 13) & 255], 1);
    }
    __syncthreads();

    // exclusive scan over 256 row counts
    pref_s[t] = cnt_s[t];
    __syncthreads();
    for (int off = 1; off < 256; off <<= 1) {
        int v = (t >= off) ? pref_s[t - off] : 0;
        __syncthreads();
        pref_s[t] += v;
        __syncthreads();
    }
    int excl = pref_s[t] - cnt_s[t];
    if (t < nr) row_start[r0 + t] = gstart + excl;
    if (bb == nbc - 1 && t == 0) row_start[NR] = nnz;
    __syncthreads();
    cnt_s[t] = excl;                 // reuse as scatter cursor
    __syncthreads();

    if (cnt <= FCAP) {
        // pass 2: scatter into LDS in exact row order, then coalesced write
        for (int k = t; k < cnt; k += 256) {
            float2 e = A[gstart + k];
            int packed = __float_as_int(e.y);
            int pos = atomicAdd(&cnt_s[(packed >> 13) & 255], 1);
            st[pos] = make_float2(e.x, __int_as_float(packed & 8191));
        }
        __syncthreads();
        for (int k = t; k < cnt; k += 256)
            B[gstart + k] = st[k];
    } else {
        // overflow (practically impossible): direct global scatter
        for (int k = t; k < cnt; k += 256) {
            float2 e = A[gstart + k];
            int packed = __float_as_int(e.y);
            int pos = atomicAdd(&cnt_s[(packed >> 13) & 255], 1);
            B[gstart + pos] = make_float2(e.x, __int_as_float(packed & 8191));
        }
    }
}

// ---------- compute: wave/row, coalesced pair load + readlane broadcast ----------

__global__ void compute_kernel(const float2* __restrict__ sorted, const int* __restrict__ row_start,
                               const float* __restrict__ W, const float* __restrict__ b,
                               float* __restrict__ out, int NR) {
    int lane = threadIdx.x & 63;
    int wv = threadIdx.x >> 6;
    int row = blockIdx.x * 4 + wv;
    if (row >= NR) return;
    int start = row_start[row];
    int end   = row_start[row + 1];
    const float2* W2 = (const float2*)W;
    float accx0 = 0.f, accy0 = 0.f, accx1 = 0.f, accy1 = 0.f;

    for (int base = start; base < end; base += 64) {
        int m = end - base;
        if (m > 64) m = 64;
        float2 p = make_float2(0.f, __int_as_float(0));
        if (lane < m) p = sorted[base + lane];
        int vi = __float_as_int(p.x);
        int ci = __float_as_int(p.y);
        int rounds = (m + 3) & ~3;
        for (int j = 0; j < rounds; j += 4) {
            float v0 = __int_as_float(__builtin_amdgcn_readlane(vi, j));
            int   c0 = __builtin_amdgcn_readlane(ci, j);
            float v1 = __int_as_float(__builtin_amdgcn_readlane(vi, j + 1));
            int   c1 = __builtin_amdgcn_readlane(ci, j + 1);
            float v2 = __int_as_float(__builtin_amdgcn_readlane(vi, j + 2));
            int   c2 = __builtin_amdgcn_readlane(ci, j + 2);
            float v3 = __int_as_float(__builtin_amdgcn_readlane(vi, j + 3));
            int   c3 = __builtin_amdgcn_readlane(ci, j + 3);
            float2 w0 = W2[c0 * 64 + lane];
            float2 w1 = W2[c1 * 64 + lane];
            float2 w2 = W2[c2 * 64 + lane];
            float2 w3 = W2[c3 * 64 + lane];
            accx0 += v0 * w0.x; accy0 += v0 * w0.y;
            accx1 += v1 * w1.x; accy1 += v1 * w1.y;
            accx0 += v2 * w2.x; accy0 += v2 * w2.y;
            accx1 += v3 * w3.x; accy1 += v3 * w3.y;
        }
    }
    float2 bb = ((const float2*)b)[lane];
    ((float2*)out)[(size_t)row * 64 + lane] =
        make_float2(accx0 + accx1 + bb.x, accy0 + accy1 + bb.y);
}

// ---------- tier-2 fallback kernels (R2 pipeline) ----------

__global__ void hist_kernel(const int* __restrict__ rows, int* __restrict__ counts, int nnz) {
    int i = blockIdx.x * blockDim.x + threadIdx.x;
    if (i < nnz) atomicAdd(&counts[rows[i]], 1);
}

__global__ void scan1_kernel(const int* __restrict__ counts, int* __restrict__ tmp,
                             int* __restrict__ bsums, int NR, int NS) {
    __shared__ int s[SCAN_BLK];
    int t = threadIdx.x;
    int i = blockIdx.x * SCAN_BLK + t;
    int x = (i < NR) ? counts[i] : 0;
    s[t] = x;
    __syncthreads();
    for (int off = 1; off < SCAN_BLK; off <<= 1) {
        int v = (t >= off) ? s[t - off] : 0;
        __syncthreads();
        s[t] += v;
        __syncthreads();
    }
    if (i < NS) tmp[i] = s[t] - x;
    if (t == SCAN_BLK - 1) bsums[blockIdx.x] = s[SCAN_BLK - 1];
}

__global__ void scan2_kernel(int* __restrict__ bsums, int nb) {
    if (threadIdx.x == 0 && blockIdx.x == 0) {
        int run = 0;
        for (int i = 0; i < nb; ++i) { int c = bsums[i]; bsums[i] = run; run += c; }
    }
}

__global__ void scan3_kernel(const int* __restrict__ tmp, const int* __restrict__ bsums,
                             int* __restrict__ row_start, int* __restrict__ cursor,
                             int NR, int NS) {
    int i = blockIdx.x * blockDim.x + threadIdx.x;
    if (i < NS) {
        int v = tmp[i] + bsums[i >> 10];
        row_start[i] = v;
        if (i < NR) cursor[i] = v;
    }
}

__global__ void scatter_sort_kernel(const float* __restrict__ vals, const int* __restrict__ rows,
                                    const int* __restrict__ cols, int* __restrict__ cursor,
                                    float2* __restrict__ sorted, int nnz) {
    int i = blockIdx.x * blockDim.x + threadIdx.x;
    if (i < nnz) {
        int r = rows[i];
        int p = atomicAdd(&cursor[r], 1);
        sorted[p] = make_float2(vals[i], __int_as_float(cols[i]));
    }
}

// ---------- tier-3 fallback (atomic path) ----------

__global__ void init_bias_kernel(float* __restrict__ out, const float* __restrict__ b, int total4) {
    const float4* b4 = (const float4*)b;
    float4* out4 = (float4*)out;
    int stride = gridDim.x * blockDim.x;
    for (int j = blockIdx.x * blockDim.x + threadIdx.x; j < total4; j += stride)
        out4[j] = b4[j & 31];
}

__global__ void scatter_atomic_kernel(const float* __restrict__ vals, const int* __restrict__ rows,
                                      const int* __restrict__ cols, const float* __restrict__ W,
                                      float* __restrict__ out, int nnz) {
    long long idx = (long long)blockIdx.x * blockDim.x + threadIdx.x;
    int i = (int)(idx >> 5);
    int c = (int)(idx & 31);
    if (i >= nnz) return;
    int row = rows[i], col = cols[i];
    float v = vals[i];
    float4 w = ((const float4*)W)[col * 32 + c];
    float* o = out + (size_t)row * UNITS + (c << 2);
    atomicAdd(o + 0, v * w.x);
    atomicAdd(o + 1, v * w.y);
    atomicAdd(o + 2, v * w.z);
    atomicAdd(o + 3, v * w.w);
}

extern "C" void kernel_launch(void* const* d_in, const int* in_sizes, int n_in,
                              void* d_out, int out_size, void* d_ws, size_t ws_size,
                              hipStream_t stream) {
    const float* vals = (const float*)d_in[0];
    const int*   rows = (const int*)d_in[1];
    const int*   cols = (const int*)d_in[2];
    const float* W    = (const float*)d_in[3];
    const float* b    = (const float*)d_in[4];
    float* out = (float*)d_out;

    const int nnz = in_sizes[0];
    const int NR  = out_size / UNITS;
    const int NS  = NR + 1;
    const int NB  = (NS + SCAN_BLK - 1) / SCAN_BLK;
    const int nbc = (NR + 255) >> 8;

    auto align = [](size_t x) { return (x + 255) & ~(size_t)255; };

    // fast-path layout
    size_t off_ccount   = 0;
    size_t off_cstart   = align(off_ccount + (size_t)nbc * 4);
    size_t off_ccur     = align(off_cstart + (size_t)(nbc + 1) * 4);
    size_t off_rowstart = align(off_ccur   + (size_t)nbc * 4);
    size_t off_sortedA  = align(off_rowstart + (size_t)NS * 4);
    size_t off_sortedB  = align(off_sortedA + (size_t)nnz * 8);
    size_t needed_full  = off_sortedB + (size_t)nnz * 8;   // ~33 MB

    // tier-2 layout (R2 pipeline)
    size_t t2_counts   = 0;
    size_t t2_tmp      = align(t2_counts + (size_t)NR * 4);
    size_t t2_bsums    = align(t2_tmp    + (size_t)NS * 4);
    size_t t2_rowstart = align(t2_bsums  + (size_t)NB * 4);
    size_t t2_cursor   = align(t2_rowstart + (size_t)NS * 4);
    size_t t2_sorted   = align(t2_cursor + (size_t)NR * 4);
    size_t needed_r2   = t2_sorted + (size_t)nnz * 8;      // ~18 MB

    char* ws = (char*)d_ws;

    if (ws_size >= needed_full) {
        int*    ccount    = (int*)(ws + off_ccount);
        int*    cstart    = (int*)(ws + off_cstart);
        int*    ccur      = (int*)(ws + off_ccur);
        int*    row_start = (int*)(ws + off_rowstart);
        float2* sortedA   = (float2*)(ws + off_sortedA);
        float2* sortedB   = (float2*)(ws + off_sortedB);

        hipMemsetAsync(ccount, 0, (size_t)nbc * 4, stream);
        coarse_hist_kernel<<<512, 256, 0, stream>>>(rows, ccount, nnz, nbc);
        coarse_scan_kernel<<<1, NBC_SLOTS, 0, stream>>>(ccount, cstart, ccur, nbc);
        {
            int grid = (nnz + CH - 1) / CH;
            partition_kernel<<<grid, 256, 0, stream>>>(vals, rows, cols, ccur, sortedA, nnz, nbc);
        }
        fine_sort_kernel<<<nbc, 256, 0, stream>>>(sortedA, sortedB, cstart, row_start, NR, nnz, nbc);
        {
            int grid = (NR + 3) / 4;
            compute_kernel<<<grid, 256, 0, stream>>>(sortedB, row_start, W, b, out, NR);
        }
    } else if (ws_size >= needed_r2) {
        int*    counts    = (int*)(ws + t2_counts);
        int*    tmp       = (int*)(ws + t2_tmp);
        int*    bsums     = (int*)(ws + t2_bsums);
        int*    row_start = (int*)(ws + t2_rowstart);
        int*    cursor    = (int*)(ws + t2_cursor);
        float2* sorted    = (float2*)(ws + t2_sorted);

        hipMemsetAsync(counts, 0, (size_t)NR * 4, stream);
        {
            int block = 256, grid = (nnz + block - 1) / block;
            hist_kernel<<<grid, block, 0, stream>>>(rows, counts, nnz);
        }
        scan1_kernel<<<NB, SCAN_BLK, 0, stream>>>(counts, tmp, bsums, NR, NS);
        scan2_kernel<<<1, 64, 0, stream>>>(bsums, NB);
        {
            int block = 256, grid = (NS + block - 1) / block;
            scan3_kernel<<<grid, block, 0, stream>>>(tmp, bsums, row_start, cursor, NR, NS);
        }
        {
            int block = 256, grid = (nnz + block - 1) / block;
            scatter_sort_kernel<<<grid, block, 0, stream>>>(vals, rows, cols, cursor, sorted, nnz);
        }
        {
            int grid = (NR + 3) / 4;
            compute_kernel<<<grid, 256, 0, stream>>>(sorted, row_start, W, b, out, NR);
        }
    } else {
        int total4 = out_size / 4;
        int block = 256;
        int grid = (total4 + block - 1) / block;
        init_bias_kernel<<<grid, block, 0, stream>>>(out, b, total4);
        long long total_threads = (long long)nnz * 32;
        long long g2 = (total_threads + block - 1) / block;
        scatter_atomic_kernel<<<(int)g2, block, 0, stream>>>(vals, rows, cols, W, out, nnz);
    }
}